// Round 6
// baseline (36.254 us; speedup 1.0000x reference)
//
#include <hip/hip_runtime.h>

typedef _Float16 f16x8 __attribute__((ext_vector_type(8)));
typedef _Float16 f16x4 __attribute__((ext_vector_type(4)));
typedef float f32x4 __attribute__((ext_vector_type(4)));

#define B_N 8192
#define K_N 256
#define DIM_N 1024

// ---------------- prep_w: U=f16(Dinv-1), W=f16(-2c*Dinv) in MFMA-fragment-PACKED layout ----------------
// pk f16-index: ((cg*32 + kc)*64 + g*16 + cl)*8 + j  where class k=(cg*16+cl), dim d=(kc*32+g*8+j).
// A wave reading pk + (cg*32+kc)*512 + lane*8 gets exactly the B-fragment (col=lane&15, k=(lane>>4)*8+j).
// Also ec[k] = -0.5*(log_det + c2): softmax_k(-0.5*acc + ec) == reference resp (row-consts cancel).
__global__ __launch_bounds__(256) void prep_w(const float* __restrict__ Dm,
                                              const float* __restrict__ Cm,
                                              _Float16* __restrict__ Upk,
                                              _Float16* __restrict__ Wpk,
                                              float* __restrict__ ec) {
    const int k = blockIdx.x, t = threadIdx.x;
    const int d = t * 4;
    const float4 dv = *(const float4*)(Dm + (size_t)k * DIM_N + d);
    const float4 cv = *(const float4*)(Cm + (size_t)k * DIM_N + d);
    float dd[4] = {dv.x, dv.y, dv.z, dv.w};
    float cc[4] = {cv.x, cv.y, cv.z, cv.w};
    f16x4 uo, wo;
    float llog = 0.f, lc2 = 0.f;
#pragma unroll
    for (int i = 0; i < 4; ++i) {
        float da = fabsf(dd[i]) + 1e-4f;
        float dinv = 1.0f / da;
        llog += logf(da);
        lc2 += cc[i] * cc[i] * dinv;
        uo[i] = (_Float16)(dinv - 1.0f);
        wo[i] = (_Float16)(-2.0f * cc[i] * dinv);
    }
    const int cg = k >> 4, cl = k & 15;
    const int kc = d >> 5, g = (d >> 3) & 3, j0 = d & 7;
    const size_t off = ((size_t)(cg * 32 + kc) * 64 + g * 16 + cl) * 8 + j0;
    *(f16x4*)(Upk + off) = uo;
    *(f16x4*)(Wpk + off) = wo;
    float both = llog + lc2;
#pragma unroll
    for (int m = 1; m <= 32; m <<= 1) both += __shfl_xor(both, m, 64);
    __shared__ float sb[4];
    if ((t & 63) == 0) sb[t >> 6] = both;
    __syncthreads();
    if (t == 0) ec[k] = -0.5f * (sb[0] + sb[1] + sb[2] + sb[3]);
}

// ---------------- gmm_gemm: zero-barrier, wave-private pipeline ----------------
// grid 256 = 128 rowp x 2 colp. Block 64x128, 4 waves (2 wr x 2 wc), wave-tile 32x64 (m2 n4).
// B (U,W) fragments: coalesced register loads from packed arrays (L2), 1 chunk ahead, 2 banks.
// A (x^2, x): wave-private LDS (4KB/buf, dbuf), staged from x-regs loaded 3 chunks ahead.
// No __syncthreads / s_barrier anywhere in the loop.
__global__ __launch_bounds__(256, 1)
void gmm_gemm(const float* __restrict__ x,
              const _Float16* __restrict__ Upk,
              const _Float16* __restrict__ Wpk,
              float* __restrict__ S) {
    __shared__ __align__(16) char lds[32768];  // 4 waves x dbuf x (A2 2KB + Ax 2KB)

    const int tid = threadIdx.x;
    const int wave = tid >> 6, lane = tid & 63;
    const int l15 = lane & 15, g4 = lane >> 4;
    const int wr = wave >> 1, wc = wave & 1;
    const int bid = blockIdx.x;
    const int rowp = bid >> 1, colp = bid & 1;
    const int bRow = rowp * 64, bCol = colp * 128;

    // x staging: lane covers rows (lane>>3)+8i (i=0..3) of the wave's 32 rows, dims (lane&7)*4..+3
    const int xr = lane >> 3, xdq = lane & 7;
    const float* xp = x + (size_t)(bRow + wr * 32 + xr) * DIM_N + xdq * 4;

    // B packed bases: frag cg = colp*8 + wc*4 + n
    const int cgb = colp * 8 + wc * 4;
    const _Float16* upb = Upk + (size_t)cgb * 32 * 512 + lane * 8;
    const _Float16* wpb = Wpk + (size_t)cgb * 32 * 512 + lane * 8;

    // wave-private LDS region: wave*8192 + sel*4096 + {A2:0, Ax:2048} + m*1024 + lane*16
    char* wlds = lds + wave * 8192;
    const int di = xdq >> 1, jb = (lane & 1) * 8;
    int awr[4];
#pragma unroll
    for (int i = 0; i < 4; ++i) {
        const int r = xr + 8 * i;
        awr[i] = ((r >> 4) << 10) + (((r & 15) + (di << 4)) << 4) + jb;
    }

    float4 xv[3][4];
    f16x8 ub[2][4], wb[2][4];
    f32x4 acc[2][4];
#pragma unroll
    for (int m = 0; m < 2; ++m)
#pragma unroll
        for (int n = 0; n < 4; ++n) { f32x4 z = {0.f, 0.f, 0.f, 0.f}; acc[m][n] = z; }

    auto issueB = [&](int bank, int c) {
#pragma unroll
        for (int n = 0; n < 4; ++n) {
            ub[bank][n] = *(const f16x8*)(upb + ((size_t)n * 32 + c) * 512);
            wb[bank][n] = *(const f16x8*)(wpb + ((size_t)n * 32 + c) * 512);
        }
    };
    auto issueX = [&](int slot, int c) {
#pragma unroll
        for (int i = 0; i < 4; ++i)
            xv[slot][i] = *(const float4*)(xp + (size_t)c * 32 + (size_t)i * 8 * DIM_N);
    };
    auto stageA = [&](int sel, int slot) {
        char* base = wlds + sel * 4096;
#pragma unroll
        for (int i = 0; i < 4; ++i) {
            const float f0 = xv[slot][i].x, f1 = xv[slot][i].y;
            const float f2 = xv[slot][i].z, f3 = xv[slot][i].w;
            f16x4 h2 = {(_Float16)(f0 * f0), (_Float16)(f1 * f1),
                        (_Float16)(f2 * f2), (_Float16)(f3 * f3)};
            f16x4 hx = {(_Float16)f0, (_Float16)f1, (_Float16)f2, (_Float16)f3};
            *(f16x4*)(base + awr[i]) = h2;           // A2 (t=0)
            *(f16x4*)(base + 2048 + awr[i]) = hx;    // Ax (t=1)
        }
    };
    auto compute = [&](int sel, int bank) {
        char* base = wlds + sel * 4096;
        f16x8 a2f[2], axf[2];
#pragma unroll
        for (int m = 0; m < 2; ++m) {
            a2f[m] = *(const f16x8*)(base + m * 1024 + lane * 16);
            axf[m] = *(const f16x8*)(base + 2048 + m * 1024 + lane * 16);
        }
        __builtin_amdgcn_s_setprio(1);
#pragma unroll
        for (int m = 0; m < 2; ++m)
#pragma unroll
            for (int n = 0; n < 4; ++n) {
                acc[m][n] = __builtin_amdgcn_mfma_f32_16x16x32_f16(a2f[m], ub[bank][n], acc[m][n], 0, 0, 0);
                acc[m][n] = __builtin_amdgcn_mfma_f32_16x16x32_f16(axf[m], wb[bank][n], acc[m][n], 0, 0, 0);
            }
        __builtin_amdgcn_s_setprio(0);
    };

    // prologue: B(0) + x(0..2) in flight; stage A(0)
    issueB(0, 0);
    issueX(0, 0); issueX(1, 1); issueX(2, 2);
    stageA(0, 0);

#pragma unroll
    for (int c = 0; c < 32; ++c) {
        const int sel = c & 1;
        if (c < 31) issueB(sel ^ 1, c + 1);          // B one chunk ahead (other bank)
        if (c < 29) issueX((c + 3) % 3, c + 3);      // x three chunks ahead
        if (c < 31) stageA(sel ^ 1, (c + 1) % 3);    // convert+transpose next chunk
        compute(sel, sel);                            // 16 MFMA on current chunk
    }

    // epilogue: raw partial (dist_sq - c2 - row_const) -> S
#pragma unroll
    for (int m = 0; m < 2; ++m) {
        const int rb = bRow + wr * 32 + m * 16 + g4 * 4;
#pragma unroll
        for (int n = 0; n < 4; ++n) {
            const int cb = bCol + wc * 64 + n * 16 + l15;
#pragma unroll
            for (int j = 0; j < 4; ++j)
                S[(size_t)(rb + j) * K_N + cb] = acc[m][n][j];
        }
    }
}

// ---------------- gmm_soft: out = softmax_k(-0.5*S + ec[k]) per row, in place ----------------
__global__ __launch_bounds__(256)
void gmm_soft(float* __restrict__ S, const float* __restrict__ ecg) {
    const int tid = threadIdx.x;
    const int wave = tid >> 6, lane = tid & 63;
    const int r = blockIdx.x * 4 + wave;
    const int k0 = lane * 4;
    float4 s = *(const float4*)(S + (size_t)r * K_N + k0);
    float4 cv = *(const float4*)(ecg + k0);
    float e[4] = {fmaf(-0.5f, s.x, cv.x), fmaf(-0.5f, s.y, cv.y),
                  fmaf(-0.5f, s.z, cv.z), fmaf(-0.5f, s.w, cv.w)};
    float m = fmaxf(fmaxf(e[0], e[1]), fmaxf(e[2], e[3]));
#pragma unroll
    for (int msk = 1; msk <= 32; msk <<= 1) m = fmaxf(m, __shfl_xor(m, msk, 64));
    float p[4], sum = 0.f;
#pragma unroll
    for (int j = 0; j < 4; ++j) {
        p[j] = __expf(e[j] - m);
        sum += p[j];
    }
#pragma unroll
    for (int msk = 1; msk <= 32; msk <<= 1) sum += __shfl_xor(sum, msk, 64);
    const float inv = 1.0f / sum;
    *(float4*)(S + (size_t)r * K_N + k0) = make_float4(p[0] * inv, p[1] * inv, p[2] * inv, p[3] * inv);
}

extern "C" void kernel_launch(void* const* d_in, const int* in_sizes, int n_in,
                              void* d_out, int out_size, void* d_ws, size_t ws_size,
                              hipStream_t stream) {
    const float* x = (const float*)d_in[0];
    const float* cen = (const float*)d_in[1];
    const float* Dm = (const float*)d_in[2];
    float* out = (float*)d_out;

    char* ws = (char*)d_ws;
    _Float16* Upk = (_Float16*)(ws);                // 512 KB packed
    _Float16* Wpk = (_Float16*)(ws + 524288);       // 512 KB packed
    float* ec = (float*)(ws + 1048576);             // 1 KB

    prep_w<<<dim3(K_N), dim3(256), 0, stream>>>(Dm, cen, Upk, Wpk, ec);
    gmm_gemm<<<dim3(256), dim3(256), 0, stream>>>(x, Upk, Wpk, out);
    gmm_soft<<<dim3(B_N / 4), dim3(256), 0, stream>>>(out, ec);
}

// Round 7
// 31.786 us; speedup vs baseline: 1.1406x; 1.1406x over previous
//
#include <hip/hip_runtime.h>

typedef _Float16 f16x8 __attribute__((ext_vector_type(8)));
typedef _Float16 f16x4 __attribute__((ext_vector_type(4)));
typedef float f32x4 __attribute__((ext_vector_type(4)));

#define B_N 8192
#define K_N 256
#define DIM_N 1024

// ---------------- prep_w: U=f16(Dinv-1), W=f16(-2c*Dinv) in MFMA-fragment-PACKED layout ----------------
// pk f16-index: ((cg*32 + kc)*64 + g*16 + cl)*8 + j  where class k=(cg*16+cl), dim d=(kc*32+g*8+j).
// A wave reading pk + (cg*32+kc)*512 + lane*8 gets exactly the B-fragment (col=lane&15, k=(lane>>4)*8+j).
// ec[k] = -0.5*(log_det + c2): softmax_k(-0.5*acc + ec) == reference resp (row-consts cancel).
__global__ __launch_bounds__(256) void prep_w(const float* __restrict__ Dm,
                                              const float* __restrict__ Cm,
                                              _Float16* __restrict__ Upk,
                                              _Float16* __restrict__ Wpk,
                                              float* __restrict__ ec) {
    const int k = blockIdx.x, t = threadIdx.x;
    const int d = t * 4;
    const float4 dv = *(const float4*)(Dm + (size_t)k * DIM_N + d);
    const float4 cv = *(const float4*)(Cm + (size_t)k * DIM_N + d);
    float dd[4] = {dv.x, dv.y, dv.z, dv.w};
    float cc[4] = {cv.x, cv.y, cv.z, cv.w};
    f16x4 uo, wo;
    float llog = 0.f, lc2 = 0.f;
#pragma unroll
    for (int i = 0; i < 4; ++i) {
        float da = fabsf(dd[i]) + 1e-4f;
        float dinv = 1.0f / da;
        llog += logf(da);
        lc2 += cc[i] * cc[i] * dinv;
        uo[i] = (_Float16)(dinv - 1.0f);
        wo[i] = (_Float16)(-2.0f * cc[i] * dinv);
    }
    const int cg = k >> 4, cl = k & 15;
    const int kc = d >> 5, g = (d >> 3) & 3, j0 = d & 7;
    const size_t off = ((size_t)(cg * 32 + kc) * 64 + g * 16 + cl) * 8 + j0;
    *(f16x4*)(Upk + off) = uo;
    *(f16x4*)(Wpk + off) = wo;
    float both = llog + lc2;
#pragma unroll
    for (int m = 1; m <= 32; m <<= 1) both += __shfl_xor(both, m, 64);
    __shared__ float sb[4];
    if ((t & 63) == 0) sb[t >> 6] = both;
    __syncthreads();
    if (t == 0) ec[k] = -0.5f * (sb[0] + sb[1] + sb[2] + sb[3]);
}

// ---------------- gmm_fused: 32 rows x 256 classes per block, GEMM + in-block softmax ----------------
// 8 waves (512 thr), wave-tile 32 rows x 32 classes (wave w owns classes w*32..w*32+31).
// B (U,W): register fragments from packed arrays (L2-resident), 2 chunks ahead, zero LDS.
// A (x^2, x f16): block LDS, XOR-swizzled, double-buffered; x f32 prefetched 6 chunks ahead.
// Softmax fused in epilogue via cross-wave LDS reduction. Chunk = 64 dims, 16 chunks.
__global__ __launch_bounds__(512, 1)
void gmm_fused(const float* __restrict__ x,
               const _Float16* __restrict__ Upk,
               const _Float16* __restrict__ Wpk,
               const float* __restrict__ ecg,
               float* __restrict__ out) {
    __shared__ __align__(16) char lds[16384];   // 2 buf x {A2 4KB | Ax 4KB}
    __shared__ float red[8][32];

    const int tid = threadIdx.x;
    const int wave = tid >> 6, lane = tid & 63;
    const int l15 = lane & 15, g4 = lane >> 4;
    const int bRow = blockIdx.x * 32;

    // x staging: thread -> row = tid>>4 (0..31), 4 dims at (tid&15)*4
    const int srow = tid >> 4, sdg = tid & 15;
    const float* xp = x + (size_t)(bRow + srow) * DIM_N + sdg * 4;
    // 8B write at swizzled slot: slot(sdg>>1) ^ (row&7), sub-offset (sdg&1)*8
    const int wByte = srow * 128 + ((((sdg >> 1) ^ (srow & 7)) << 4) | ((sdg & 1) << 3));

    // B packed bases: wave's class-groups cg = wave*2 + n
    const _Float16* upb = Upk + (size_t)(wave * 2) * 32 * 512 + lane * 8;
    const _Float16* wpb = Wpk + (size_t)(wave * 2) * 32 * 512 + lane * 8;

    // A-frag read offsets: frag(m,k2): row = m*16+l15, slot = k2*4+g4 (^ row&7)
    int aRd[2][2];
#pragma unroll
    for (int m = 0; m < 2; ++m)
#pragma unroll
        for (int k2 = 0; k2 < 2; ++k2) {
            const int row = m * 16 + l15;
            aRd[m][k2] = row * 128 + ((((k2 * 4 + g4) ^ (row & 7)) << 4));
        }

    f32x4 acc[2][2];
#pragma unroll
    for (int m = 0; m < 2; ++m)
#pragma unroll
        for (int n = 0; n < 2; ++n) { f32x4 z = {0.f, 0.f, 0.f, 0.f}; acc[m][n] = z; }

    float4 xv[6];                 // 6-deep x prefetch (~1000 cy of cover)
    f16x8 ub[2][2][2], wb[2][2][2];  // [bank][n][k2]

    auto issueX = [&](int slot, int c) { xv[slot] = *(const float4*)(xp + c * 64); };
    auto issueB = [&](int bank, int c) {
#pragma unroll
        for (int n = 0; n < 2; ++n)
#pragma unroll
            for (int k2 = 0; k2 < 2; ++k2) {
                const int kc = c * 2 + k2;
                ub[bank][n][k2] = *(const f16x8*)(upb + (size_t)(n * 32 + kc) * 512);
                wb[bank][n][k2] = *(const f16x8*)(wpb + (size_t)(n * 32 + kc) * 512);
            }
    };
    auto stage = [&](int sel, int slot) {
        char* base = lds + sel * 8192;
        const float f0 = xv[slot].x, f1 = xv[slot].y, f2 = xv[slot].z, f3 = xv[slot].w;
        f16x4 h2 = {(_Float16)(f0 * f0), (_Float16)(f1 * f1),
                    (_Float16)(f2 * f2), (_Float16)(f3 * f3)};
        f16x4 hx = {(_Float16)f0, (_Float16)f1, (_Float16)f2, (_Float16)f3};
        *(f16x4*)(base + wByte) = h2;           // A2
        *(f16x4*)(base + 4096 + wByte) = hx;    // Ax
    };
    auto compute = [&](int sel, int bank) {
        char* base = lds + sel * 8192;
        f16x8 a2f[2][2], axf[2][2];
#pragma unroll
        for (int m = 0; m < 2; ++m)
#pragma unroll
            for (int k2 = 0; k2 < 2; ++k2) {
                a2f[m][k2] = *(const f16x8*)(base + aRd[m][k2]);
                axf[m][k2] = *(const f16x8*)(base + 4096 + aRd[m][k2]);
            }
        __builtin_amdgcn_s_setprio(1);
#pragma unroll
        for (int m = 0; m < 2; ++m)
#pragma unroll
            for (int n = 0; n < 2; ++n)
#pragma unroll
                for (int k2 = 0; k2 < 2; ++k2) {
                    acc[m][n] = __builtin_amdgcn_mfma_f32_16x16x32_f16(a2f[m][k2], ub[bank][n][k2], acc[m][n], 0, 0, 0);
                    acc[m][n] = __builtin_amdgcn_mfma_f32_16x16x32_f16(axf[m][k2], wb[bank][n][k2], acc[m][n], 0, 0, 0);
                }
        __builtin_amdgcn_s_setprio(0);
    };

    // ---- prologue: B chunks 0,1 + x chunks 0..5 in flight; stage chunk 0 ----
    issueB(0, 0);
    issueB(1, 1);
#pragma unroll
    for (int s = 0; s < 6; ++s) issueX(s, s);
    stage(0, 0);
    asm volatile("s_waitcnt lgkmcnt(0)" ::: "memory");
    __builtin_amdgcn_s_barrier();
    __builtin_amdgcn_sched_barrier(0);

#pragma unroll
    for (int c = 0; c < 16; ++c) {
        const int sel = c & 1;
        if (c < 10) issueX(c % 6, c + 6);           // x six chunks ahead
        if (c < 15) stage(sel ^ 1, (c + 1) % 6);    // convert+stage next chunk
        compute(sel, sel);                           // 16 MFMA on current chunk
        if (c < 14) issueB(sel, c + 2);             // B two chunks ahead (freed bank)
        if (c < 15) {
            asm volatile("s_waitcnt lgkmcnt(0)" ::: "memory");
            __builtin_amdgcn_s_barrier();
            __builtin_amdgcn_sched_barrier(0);
        }
    }

    // ---- fused epilogue: e = -0.5*acc + ec[k]; weighted row softmax across waves ----
    const int cls0 = wave * 32 + l15;
    const float ecv[2] = {ecg[cls0], ecg[cls0 + 16]};

    float e[2][2][4];
#pragma unroll
    for (int m = 0; m < 2; ++m)
#pragma unroll
        for (int n = 0; n < 2; ++n)
#pragma unroll
            for (int j = 0; j < 4; ++j)
                e[m][n][j] = fmaf(-0.5f, acc[m][n][j], ecv[n]);

    float mx[2][4];
#pragma unroll
    for (int m = 0; m < 2; ++m)
#pragma unroll
        for (int j = 0; j < 4; ++j) mx[m][j] = fmaxf(e[m][0][j], e[m][1][j]);
#pragma unroll
    for (int msk = 1; msk <= 8; msk <<= 1)
#pragma unroll
        for (int m = 0; m < 2; ++m)
#pragma unroll
            for (int j = 0; j < 4; ++j)
                mx[m][j] = fmaxf(mx[m][j], __shfl_xor(mx[m][j], msk, 64));
    if (l15 == 0) {
#pragma unroll
        for (int m = 0; m < 2; ++m)
#pragma unroll
            for (int j = 0; j < 4; ++j) red[wave][m * 16 + g4 * 4 + j] = mx[m][j];
    }
    __syncthreads();
    float gm[2][4];
#pragma unroll
    for (int m = 0; m < 2; ++m)
#pragma unroll
        for (int j = 0; j < 4; ++j) {
            const int r = m * 16 + g4 * 4 + j;
            float v = red[0][r];
#pragma unroll
            for (int w = 1; w < 8; ++w) v = fmaxf(v, red[w][r]);
            gm[m][j] = v;
        }
    __syncthreads();

    float p[2][2][4], sm[2][4];
#pragma unroll
    for (int m = 0; m < 2; ++m)
#pragma unroll
        for (int j = 0; j < 4; ++j) sm[m][j] = 0.f;
#pragma unroll
    for (int m = 0; m < 2; ++m)
#pragma unroll
        for (int n = 0; n < 2; ++n)
#pragma unroll
            for (int j = 0; j < 4; ++j) {
                p[m][n][j] = __expf(e[m][n][j] - gm[m][j]);
                sm[m][j] += p[m][n][j];
            }
#pragma unroll
    for (int msk = 1; msk <= 8; msk <<= 1)
#pragma unroll
        for (int m = 0; m < 2; ++m)
#pragma unroll
            for (int j = 0; j < 4; ++j) sm[m][j] += __shfl_xor(sm[m][j], msk, 64);
    if (l15 == 0) {
#pragma unroll
        for (int m = 0; m < 2; ++m)
#pragma unroll
            for (int j = 0; j < 4; ++j) red[wave][m * 16 + g4 * 4 + j] = sm[m][j];
    }
    __syncthreads();
#pragma unroll
    for (int m = 0; m < 2; ++m)
#pragma unroll
        for (int j = 0; j < 4; ++j) {
            const int r = m * 16 + g4 * 4 + j;
            float t = red[0][r];
#pragma unroll
            for (int w = 1; w < 8; ++w) t += red[w][r];
            const float inv = 1.0f / t;
#pragma unroll
            for (int n = 0; n < 2; ++n)
                out[(size_t)(bRow + r) * K_N + cls0 + n * 16] = p[m][n][j] * inv;
        }
}

extern "C" void kernel_launch(void* const* d_in, const int* in_sizes, int n_in,
                              void* d_out, int out_size, void* d_ws, size_t ws_size,
                              hipStream_t stream) {
    const float* x = (const float*)d_in[0];
    const float* cen = (const float*)d_in[1];
    const float* Dm = (const float*)d_in[2];
    float* out = (float*)d_out;

    char* ws = (char*)d_ws;
    _Float16* Upk = (_Float16*)(ws);                // 512 KB packed
    _Float16* Wpk = (_Float16*)(ws + 524288);       // 512 KB packed
    float* ec = (float*)(ws + 1048576);             // 1 KB

    prep_w<<<dim3(K_N), dim3(256), 0, stream>>>(Dm, cen, Upk, Wpk, ec);
    gmm_fused<<<dim3(B_N / 32), dim3(512), 0, stream>>>(x, Upk, Wpk, ec, out);
}

// Round 8
// 30.675 us; speedup vs baseline: 1.1819x; 1.0362x over previous
//
#include <hip/hip_runtime.h>

typedef _Float16 f16x8 __attribute__((ext_vector_type(8)));
typedef _Float16 f16x4 __attribute__((ext_vector_type(4)));
typedef float f32x4 __attribute__((ext_vector_type(4)));

#define B_N 8192
#define K_N 256
#define DIM_N 1024

// ---------------- prep_w: U=f16(Dinv-1), W=f16(-2c*Dinv) in MFMA-fragment-PACKED layout ----------------
// pk f16-index: ((cg*32 + kc)*64 + g*16 + cl)*8 + j  where class k=(cg*16+cl), dim d=(kc*32+g*8+j).
// A wave reading pk + (cg*32+kc)*512 + lane*8 gets exactly the B-fragment (col=lane&15, k=(lane>>4)*8+j).
// ec[k] = -0.5*(log_det + c2): softmax_k(-0.5*acc + ec) == reference resp (row-consts cancel).
__global__ __launch_bounds__(256) void prep_w(const float* __restrict__ Dm,
                                              const float* __restrict__ Cm,
                                              _Float16* __restrict__ Upk,
                                              _Float16* __restrict__ Wpk,
                                              float* __restrict__ ec) {
    const int k = blockIdx.x, t = threadIdx.x;
    const int d = t * 4;
    const float4 dv = *(const float4*)(Dm + (size_t)k * DIM_N + d);
    const float4 cv = *(const float4*)(Cm + (size_t)k * DIM_N + d);
    float dd[4] = {dv.x, dv.y, dv.z, dv.w};
    float cc[4] = {cv.x, cv.y, cv.z, cv.w};
    f16x4 uo, wo;
    float llog = 0.f, lc2 = 0.f;
#pragma unroll
    for (int i = 0; i < 4; ++i) {
        float da = fabsf(dd[i]) + 1e-4f;
        float dinv = 1.0f / da;
        llog += logf(da);
        lc2 += cc[i] * cc[i] * dinv;
        uo[i] = (_Float16)(dinv - 1.0f);
        wo[i] = (_Float16)(-2.0f * cc[i] * dinv);
    }
    const int cg = k >> 4, cl = k & 15;
    const int kc = d >> 5, g = (d >> 3) & 3, j0 = d & 7;
    const size_t off = ((size_t)(cg * 32 + kc) * 64 + g * 16 + cl) * 8 + j0;
    *(f16x4*)(Upk + off) = uo;
    *(f16x4*)(Wpk + off) = wo;
    float both = llog + lc2;
#pragma unroll
    for (int m = 1; m <= 32; m <<= 1) both += __shfl_xor(both, m, 64);
    __shared__ float sb[4];
    if ((t & 63) == 0) sb[t >> 6] = both;
    __syncthreads();
    if (t == 0) ec[k] = -0.5f * (sb[0] + sb[1] + sb[2] + sb[3]);
}

// ---------------- gmm_fused: 32 rows x 256 classes per block; 8 phases of 128 dims ----------------
// 8 waves (512 thr), wave w owns classes w*32..w*32+31 (wave-tile 32x32, m2n2, 2 products).
// B (U,W): register fragments from packed arrays (L2-resident), 2-chunk (1-phase) lead, 2 banks.
// A (x^2, x f16): block LDS (2 buf x 16KB), XOR-swizzled; x f32 prefetched 6 chunks (3 phases) ahead.
// One lgkmcnt(0)+s_barrier per 128-dim phase (8 total); global loads stay in flight across barriers.
__global__ __launch_bounds__(512, 1)
void gmm_fused(const float* __restrict__ x,
               const _Float16* __restrict__ Upk,
               const _Float16* __restrict__ Wpk,
               const float* __restrict__ ecg,
               float* __restrict__ out) {
    __shared__ __align__(16) char lds[32768];   // buf*16384 + {A2: sub*4096 | Ax: 8192+sub*4096}
    __shared__ float red[8][32];

    const int tid = threadIdx.x;
    const int wave = tid >> 6, lane = tid & 63;
    const int l15 = lane & 15, g4 = lane >> 4;
    const int bRow = blockIdx.x * 32;

    // x staging: thread -> row = tid>>4 (0..31), 4 dims at (tid&15)*4 within a 64-dim chunk
    const int srow = tid >> 4, sdg = tid & 15;
    const float* xp = x + (size_t)(bRow + srow) * DIM_N + sdg * 4;
    const int wByte = srow * 128 + ((((sdg >> 1) ^ (srow & 7)) << 4) | ((sdg & 1) << 3));

    // B packed bases: wave's class-groups cg = wave*2 + n
    const _Float16* upb = Upk + (size_t)(wave * 2) * 32 * 512 + lane * 8;
    const _Float16* wpb = Wpk + (size_t)(wave * 2) * 32 * 512 + lane * 8;

    // A-frag read offsets within a 4KB chunk-tile
    int aRd[2][2];
#pragma unroll
    for (int m = 0; m < 2; ++m)
#pragma unroll
        for (int k2 = 0; k2 < 2; ++k2) {
            const int row = m * 16 + l15;
            aRd[m][k2] = row * 128 + ((((k2 * 4 + g4) ^ (row & 7)) << 4));
        }

    f32x4 acc[2][2];
#pragma unroll
    for (int m = 0; m < 2; ++m)
#pragma unroll
        for (int n = 0; n < 2; ++n) { f32x4 z = {0.f, 0.f, 0.f, 0.f}; acc[m][n] = z; }

    float4 xv[6];                    // 6-chunk-deep x prefetch
    f16x8 ub[2][2][2], wb[2][2][2];  // [chunk-parity bank][n][k2]

    auto issueX = [&](int slot, int c) { xv[slot] = *(const float4*)(xp + c * 64); };
    auto issueB = [&](int bank, int c) {
#pragma unroll
        for (int n = 0; n < 2; ++n)
#pragma unroll
            for (int k2 = 0; k2 < 2; ++k2) {
                const int kc = c * 2 + k2;
                ub[bank][n][k2] = *(const f16x8*)(upb + (size_t)(n * 32 + kc) * 512);
                wb[bank][n][k2] = *(const f16x8*)(wpb + (size_t)(n * 32 + kc) * 512);
            }
    };
    auto stage1 = [&](int buf, int sub, int slot) {
        char* base = lds + buf * 16384 + sub * 4096;
        const float f0 = xv[slot].x, f1 = xv[slot].y, f2 = xv[slot].z, f3 = xv[slot].w;
        f16x4 h2 = {(_Float16)(f0 * f0), (_Float16)(f1 * f1),
                    (_Float16)(f2 * f2), (_Float16)(f3 * f3)};
        f16x4 hx = {(_Float16)f0, (_Float16)f1, (_Float16)f2, (_Float16)f3};
        *(f16x4*)(base + wByte) = h2;           // A2
        *(f16x4*)(base + 8192 + wByte) = hx;    // Ax
    };
    auto compute = [&](int buf, int sub, int bank) {
        char* base = lds + buf * 16384 + sub * 4096;
        f16x8 a2f[2][2], axf[2][2];
#pragma unroll
        for (int m = 0; m < 2; ++m)
#pragma unroll
            for (int k2 = 0; k2 < 2; ++k2) {
                a2f[m][k2] = *(const f16x8*)(base + aRd[m][k2]);
                axf[m][k2] = *(const f16x8*)(base + 8192 + aRd[m][k2]);
            }
#pragma unroll
        for (int m = 0; m < 2; ++m)
#pragma unroll
            for (int n = 0; n < 2; ++n)
#pragma unroll
                for (int k2 = 0; k2 < 2; ++k2) {
                    acc[m][n] = __builtin_amdgcn_mfma_f32_16x16x32_f16(a2f[m][k2], ub[bank][n][k2], acc[m][n], 0, 0, 0);
                    acc[m][n] = __builtin_amdgcn_mfma_f32_16x16x32_f16(axf[m][k2], wb[bank][n][k2], acc[m][n], 0, 0, 0);
                }
    };

    // ---- prologue: B chunks 0,1 + x chunks 0..5 in flight; stage phase 0 (chunks 0,1) ----
    issueB(0, 0);
    issueB(1, 1);
#pragma unroll
    for (int s = 0; s < 6; ++s) issueX(s, s);
    stage1(0, 0, 0);
    stage1(0, 1, 1);
    asm volatile("s_waitcnt lgkmcnt(0)" ::: "memory");
    __builtin_amdgcn_s_barrier();
    __builtin_amdgcn_sched_barrier(0);

#pragma unroll
    for (int p = 0; p < 8; ++p) {
        const int buf = p & 1, nbuf = buf ^ 1;
        // x: 3 phases (6 chunks) ahead
        if (p < 5) { issueX((2 * p) % 6, 2 * p + 6); issueX((2 * p + 1) % 6, 2 * p + 7); }
        // stage next phase's chunks into the other buffer
        if (p < 7) { stage1(nbuf, 0, (2 * p + 2) % 6); stage1(nbuf, 1, (2 * p + 3) % 6); }
        // compute this phase's two chunks; re-issue B for phase p+1 as banks free up
        compute(buf, 0, 0);
        if (p < 7) issueB(0, 2 * p + 2);
        compute(buf, 1, 1);
        if (p < 7) issueB(1, 2 * p + 3);
        if (p < 7) {
            asm volatile("s_waitcnt lgkmcnt(0)" ::: "memory");
            __builtin_amdgcn_s_barrier();
            __builtin_amdgcn_sched_barrier(0);
        }
    }

    // ---- fused epilogue: e = -0.5*acc + ec[k]; weighted row softmax across waves ----
    const int cls0 = wave * 32 + l15;
    const float ecv[2] = {ecg[cls0], ecg[cls0 + 16]};

    float e[2][2][4];
#pragma unroll
    for (int m = 0; m < 2; ++m)
#pragma unroll
        for (int n = 0; n < 2; ++n)
#pragma unroll
            for (int j = 0; j < 4; ++j)
                e[m][n][j] = fmaf(-0.5f, acc[m][n][j], ecv[n]);

    float mx[2][4];
#pragma unroll
    for (int m = 0; m < 2; ++m)
#pragma unroll
        for (int j = 0; j < 4; ++j) mx[m][j] = fmaxf(e[m][0][j], e[m][1][j]);
#pragma unroll
    for (int msk = 1; msk <= 8; msk <<= 1)
#pragma unroll
        for (int m = 0; m < 2; ++m)
#pragma unroll
            for (int j = 0; j < 4; ++j)
                mx[m][j] = fmaxf(mx[m][j], __shfl_xor(mx[m][j], msk, 64));
    if (l15 == 0) {
#pragma unroll
        for (int m = 0; m < 2; ++m)
#pragma unroll
            for (int j = 0; j < 4; ++j) red[wave][m * 16 + g4 * 4 + j] = mx[m][j];
    }
    __syncthreads();
    float gm[2][4];
#pragma unroll
    for (int m = 0; m < 2; ++m)
#pragma unroll
        for (int j = 0; j < 4; ++j) {
            const int r = m * 16 + g4 * 4 + j;
            float v = red[0][r];
#pragma unroll
            for (int w = 1; w < 8; ++w) v = fmaxf(v, red[w][r]);
            gm[m][j] = v;
        }
    __syncthreads();

    float p2[2][2][4], sm[2][4];
#pragma unroll
    for (int m = 0; m < 2; ++m)
#pragma unroll
        for (int j = 0; j < 4; ++j) sm[m][j] = 0.f;
#pragma unroll
    for (int m = 0; m < 2; ++m)
#pragma unroll
        for (int n = 0; n < 2; ++n)
#pragma unroll
            for (int j = 0; j < 4; ++j) {
                p2[m][n][j] = __expf(e[m][n][j] - gm[m][j]);
                sm[m][j] += p2[m][n][j];
            }
#pragma unroll
    for (int msk = 1; msk <= 8; msk <<= 1)
#pragma unroll
        for (int m = 0; m < 2; ++m)
#pragma unroll
            for (int j = 0; j < 4; ++j) sm[m][j] += __shfl_xor(sm[m][j], msk, 64);
    if (l15 == 0) {
#pragma unroll
        for (int m = 0; m < 2; ++m)
#pragma unroll
            for (int j = 0; j < 4; ++j) red[wave][m * 16 + g4 * 4 + j] = sm[m][j];
    }
    __syncthreads();
#pragma unroll
    for (int m = 0; m < 2; ++m)
#pragma unroll
        for (int j = 0; j < 4; ++j) {
            const int r = m * 16 + g4 * 4 + j;
            float t = red[0][r];
#pragma unroll
            for (int w = 1; w < 8; ++w) t += red[w][r];
            const float inv = 1.0f / t;
#pragma unroll
            for (int n = 0; n < 2; ++n)
                out[(size_t)(bRow + r) * K_N + cls0 + n * 16] = p2[m][n][j] * inv;
        }
}

extern "C" void kernel_launch(void* const* d_in, const int* in_sizes, int n_in,
                              void* d_out, int out_size, void* d_ws, size_t ws_size,
                              hipStream_t stream) {
    const float* x = (const float*)d_in[0];
    const float* cen = (const float*)d_in[1];
    const float* Dm = (const float*)d_in[2];
    float* out = (float*)d_out;

    char* ws = (char*)d_ws;
    _Float16* Upk = (_Float16*)(ws);                // 512 KB packed
    _Float16* Wpk = (_Float16*)(ws + 524288);       // 512 KB packed
    float* ec = (float*)(ws + 1048576);             // 1 KB

    prep_w<<<dim3(K_N), dim3(256), 0, stream>>>(Dm, cen, Upk, Wpk, ec);
    gmm_fused<<<dim3(B_N / 32), dim3(512), 0, stream>>>(x, Upk, Wpk, ec, out);
}

// Round 9
// 29.993 us; speedup vs baseline: 1.2087x; 1.0227x over previous
//
#include <hip/hip_runtime.h>

typedef _Float16 f16x8 __attribute__((ext_vector_type(8)));
typedef _Float16 f16x4 __attribute__((ext_vector_type(4)));
typedef float f32x4 __attribute__((ext_vector_type(4)));

#define B_N 8192
#define K_N 256
#define DIM_N 1024

// ---------------- prep_w: U=f16(Dinv-1), W=f16(-2c*Dinv) in MFMA-fragment-PACKED layout ----------------
// pk f16-index: ((cg*32 + kc)*64 + g*16 + cl)*8 + j  where class k=(cg*16+cl), dim d=(kc*32+g*8+j).
// A wave reading pk + (cg*32+kc)*512 + lane*8 gets exactly the B-fragment (col=lane&15, k=(lane>>4)*8+j).
// ec[k] = -0.5*(log_det + c2): softmax_k(-0.5*acc + ec) == reference resp (row-consts cancel).
__global__ __launch_bounds__(256) void prep_w(const float* __restrict__ Dm,
                                              const float* __restrict__ Cm,
                                              _Float16* __restrict__ Upk,
                                              _Float16* __restrict__ Wpk,
                                              float* __restrict__ ec) {
    const int k = blockIdx.x, t = threadIdx.x;
    const int d = t * 4;
    const float4 dv = *(const float4*)(Dm + (size_t)k * DIM_N + d);
    const float4 cv = *(const float4*)(Cm + (size_t)k * DIM_N + d);
    float dd[4] = {dv.x, dv.y, dv.z, dv.w};
    float cc[4] = {cv.x, cv.y, cv.z, cv.w};
    f16x4 uo, wo;
    float llog = 0.f, lc2 = 0.f;
#pragma unroll
    for (int i = 0; i < 4; ++i) {
        float da = fabsf(dd[i]) + 1e-4f;
        float dinv = 1.0f / da;
        llog += logf(da);
        lc2 += cc[i] * cc[i] * dinv;
        uo[i] = (_Float16)(dinv - 1.0f);
        wo[i] = (_Float16)(-2.0f * cc[i] * dinv);
    }
    const int cg = k >> 4, cl = k & 15;
    const int kc = d >> 5, g = (d >> 3) & 3, j0 = d & 7;
    const size_t off = ((size_t)(cg * 32 + kc) * 64 + g * 16 + cl) * 8 + j0;
    *(f16x4*)(Upk + off) = uo;
    *(f16x4*)(Wpk + off) = wo;
    float both = llog + lc2;
#pragma unroll
    for (int m = 1; m <= 32; m <<= 1) both += __shfl_xor(both, m, 64);
    __shared__ float sb[4];
    if ((t & 63) == 0) sb[t >> 6] = both;
    __syncthreads();
    if (t == 0) ec[k] = -0.5f * (sb[0] + sb[1] + sb[2] + sb[3]);
}

// ---------------- gmm_fused: 32 rows x 256 classes; x staged ONCE (4 quarters), 4 barriers total ----------------
// 8 waves (512 thr), wave w owns classes w*32..w*32+31 (wave-tile 32x32, m2n2, 2 products).
// x f16 lives in 64KB LDS for the whole kernel (quarter q = chunks 4q..4q+3, never overwritten).
// x^2 fragments computed in-register from x fragments (v_pk_mul_f16) -> halves LDS traffic.
// B (U,W): register fragments from packed arrays (L2-resident), 2 banks, issued ~2 chunks ahead;
// global loads stay in flight across the 4 quarter barriers (only lgkmcnt is drained).
__global__ __launch_bounds__(512, 1)
void gmm_fused(const float* __restrict__ x,
               const _Float16* __restrict__ Upk,
               const _Float16* __restrict__ Wpk,
               const float* __restrict__ ecg,
               float* __restrict__ out) {
    __shared__ __align__(16) char xlds[65536];  // 4 quarters x [32 rows][256 dims] f16, XOR-swizzled
    __shared__ float red[8][32];

    const int tid = threadIdx.x;
    const int wave = tid >> 6, lane = tid & 63;
    const int l15 = lane & 15, g4 = lane >> 4;
    const int bRow = blockIdx.x * 32;

    // staging: thread -> row = tid>>4 (0..31); dims sd + 64*j (j=0..3) within a 256-dim quarter
    const int srow = tid >> 4, sd = (tid & 15) * 4;
    const float* xq = x + (size_t)(bRow + srow) * DIM_N + sd;
    int wB[4];
#pragma unroll
    for (int j = 0; j < 4; ++j) {
        const int slot = (sd >> 3) + 8 * j;
        wB[j] = srow * 512 + (((slot ^ (srow & 7)) << 4) | ((sd & 4) << 1));
    }

    // B packed bases: wave's class-groups cg = wave*2 + n
    const _Float16* upb = Upk + (size_t)(wave * 2) * 32 * 512 + lane * 8;
    const _Float16* wpb = Wpk + (size_t)(wave * 2) * 32 * 512 + lane * 8;

    f32x4 acc[2][2];
#pragma unroll
    for (int m = 0; m < 2; ++m)
#pragma unroll
        for (int n = 0; n < 2; ++n) { f32x4 z = {0.f, 0.f, 0.f, 0.f}; acc[m][n] = z; }

    float4 xs[2][4];                 // staging regs, 2 quarter-banks
    f16x8 ub[2][2][2], wb[2][2][2];  // [bank][n][k2]

    auto issueQ = [&](int bank, int q) {
#pragma unroll
        for (int j = 0; j < 4; ++j) xs[bank][j] = *(const float4*)(xq + q * 256 + j * 64);
    };
    auto writeQ = [&](int bank, int q) {
        char* base = xlds + q * 16384;
#pragma unroll
        for (int j = 0; j < 4; ++j) {
            const float4 v = xs[bank][j];
            f16x4 h = {(_Float16)v.x, (_Float16)v.y, (_Float16)v.z, (_Float16)v.w};
            *(f16x4*)(base + wB[j]) = h;
        }
    };
    auto issueB = [&](int bank, int c) {
#pragma unroll
        for (int n = 0; n < 2; ++n)
#pragma unroll
            for (int k2 = 0; k2 < 2; ++k2) {
                const int kc = c * 2 + k2;
                ub[bank][n][k2] = *(const f16x8*)(upb + (size_t)(n * 32 + kc) * 512);
                wb[bank][n][k2] = *(const f16x8*)(wpb + (size_t)(n * 32 + kc) * 512);
            }
    };
    auto compute = [&](int c, int bank) {
        const char* base = xlds + (c >> 2) * 16384;
        const int cl = c & 3;
        f16x8 axf[2][2], a2f[2][2];
#pragma unroll
        for (int m = 0; m < 2; ++m)
#pragma unroll
            for (int k2 = 0; k2 < 2; ++k2) {
                const int row = m * 16 + l15;
                const int slot = cl * 8 + k2 * 4 + g4;
                axf[m][k2] = *(const f16x8*)(base + row * 512 + (((slot ^ (l15 & 7)) << 4)));
                a2f[m][k2] = axf[m][k2] * axf[m][k2];   // x^2 in-register (v_pk_mul_f16)
            }
        __builtin_amdgcn_s_setprio(1);
#pragma unroll
        for (int m = 0; m < 2; ++m)
#pragma unroll
            for (int n = 0; n < 2; ++n)
#pragma unroll
                for (int k2 = 0; k2 < 2; ++k2) {
                    acc[m][n] = __builtin_amdgcn_mfma_f32_16x16x32_f16(a2f[m][k2], ub[bank][n][k2], acc[m][n], 0, 0, 0);
                    acc[m][n] = __builtin_amdgcn_mfma_f32_16x16x32_f16(axf[m][k2], wb[bank][n][k2], acc[m][n], 0, 0, 0);
                }
        __builtin_amdgcn_s_setprio(0);
    };

    // ---- staging pipeline + K-loop: 4 barriers total ----
    issueB(0, 0); issueB(1, 1);
    issueQ(0, 0); issueQ(1, 1);
    writeQ(0, 0);
    issueQ(0, 2);
    asm volatile("s_waitcnt lgkmcnt(0)" ::: "memory");
    __builtin_amdgcn_s_barrier();              // quarter 0 ready
    __builtin_amdgcn_sched_barrier(0);
    writeQ(1, 1);
    issueQ(1, 3);
    compute(0, 0); issueB(0, 2);
    compute(1, 1); issueB(1, 3);
    compute(2, 0); issueB(0, 4);
    compute(3, 1); issueB(1, 5);
    asm volatile("s_waitcnt lgkmcnt(0)" ::: "memory");
    __builtin_amdgcn_s_barrier();              // quarter 1 ready
    __builtin_amdgcn_sched_barrier(0);
    writeQ(0, 2);
    compute(4, 0); issueB(0, 6);
    compute(5, 1); issueB(1, 7);
    compute(6, 0); issueB(0, 8);
    compute(7, 1); issueB(1, 9);
    asm volatile("s_waitcnt lgkmcnt(0)" ::: "memory");
    __builtin_amdgcn_s_barrier();              // quarter 2 ready
    __builtin_amdgcn_sched_barrier(0);
    writeQ(1, 3);
    compute(8, 0);  issueB(0, 10);
    compute(9, 1);  issueB(1, 11);
    compute(10, 0); issueB(0, 12);
    compute(11, 1); issueB(1, 13);
    asm volatile("s_waitcnt lgkmcnt(0)" ::: "memory");
    __builtin_amdgcn_s_barrier();              // quarter 3 ready
    __builtin_amdgcn_sched_barrier(0);
    compute(12, 0); issueB(0, 14);
    compute(13, 1); issueB(1, 15);
    compute(14, 0);
    compute(15, 1);

    // ---- fused epilogue: e = -0.5*acc + ec[k]; weighted row softmax across waves ----
    const int cls0 = wave * 32 + l15;
    const float ecv[2] = {ecg[cls0], ecg[cls0 + 16]};

    float e[2][2][4];
#pragma unroll
    for (int m = 0; m < 2; ++m)
#pragma unroll
        for (int n = 0; n < 2; ++n)
#pragma unroll
            for (int j = 0; j < 4; ++j)
                e[m][n][j] = fmaf(-0.5f, acc[m][n][j], ecv[n]);

    float mx[2][4];
#pragma unroll
    for (int m = 0; m < 2; ++m)
#pragma unroll
        for (int j = 0; j < 4; ++j) mx[m][j] = fmaxf(e[m][0][j], e[m][1][j]);
#pragma unroll
    for (int msk = 1; msk <= 8; msk <<= 1)
#pragma unroll
        for (int m = 0; m < 2; ++m)
#pragma unroll
            for (int j = 0; j < 4; ++j)
                mx[m][j] = fmaxf(mx[m][j], __shfl_xor(mx[m][j], msk, 64));
    if (l15 == 0) {
#pragma unroll
        for (int m = 0; m < 2; ++m)
#pragma unroll
            for (int j = 0; j < 4; ++j) red[wave][m * 16 + g4 * 4 + j] = mx[m][j];
    }
    __syncthreads();
    float gm[2][4];
#pragma unroll
    for (int m = 0; m < 2; ++m)
#pragma unroll
        for (int j = 0; j < 4; ++j) {
            const int r = m * 16 + g4 * 4 + j;
            float v = red[0][r];
#pragma unroll
            for (int w = 1; w < 8; ++w) v = fmaxf(v, red[w][r]);
            gm[m][j] = v;
        }
    __syncthreads();

    float p2[2][2][4], sm[2][4];
#pragma unroll
    for (int m = 0; m < 2; ++m)
#pragma unroll
        for (int j = 0; j < 4; ++j) sm[m][j] = 0.f;
#pragma unroll
    for (int m = 0; m < 2; ++m)
#pragma unroll
        for (int n = 0; n < 2; ++n)
#pragma unroll
            for (int j = 0; j < 4; ++j) {
                p2[m][n][j] = __expf(e[m][n][j] - gm[m][j]);
                sm[m][j] += p2[m][n][j];
            }
#pragma unroll
    for (int msk = 1; msk <= 8; msk <<= 1)
#pragma unroll
        for (int m = 0; m < 2; ++m)
#pragma unroll
            for (int j = 0; j < 4; ++j) sm[m][j] += __shfl_xor(sm[m][j], msk, 64);
    if (l15 == 0) {
#pragma unroll
        for (int m = 0; m < 2; ++m)
#pragma unroll
            for (int j = 0; j < 4; ++j) red[wave][m * 16 + g4 * 4 + j] = sm[m][j];
    }
    __syncthreads();
#pragma unroll
    for (int m = 0; m < 2; ++m)
#pragma unroll
        for (int j = 0; j < 4; ++j) {
            const int r = m * 16 + g4 * 4 + j;
            float t = red[0][r];
#pragma unroll
            for (int w = 1; w < 8; ++w) t += red[w][r];
            const float inv = 1.0f / t;
#pragma unroll
            for (int n = 0; n < 2; ++n)
                out[(size_t)(bRow + r) * K_N + cls0 + n * 16] = p2[m][n][j] * inv;
        }
}

extern "C" void kernel_launch(void* const* d_in, const int* in_sizes, int n_in,
                              void* d_out, int out_size, void* d_ws, size_t ws_size,
                              hipStream_t stream) {
    const float* x = (const float*)d_in[0];
    const float* cen = (const float*)d_in[1];
    const float* Dm = (const float*)d_in[2];
    float* out = (float*)d_out;

    char* ws = (char*)d_ws;
    _Float16* Upk = (_Float16*)(ws);                // 512 KB packed
    _Float16* Wpk = (_Float16*)(ws + 524288);       // 512 KB packed
    float* ec = (float*)(ws + 1048576);             // 1 KB

    prep_w<<<dim3(K_N), dim3(256), 0, stream>>>(Dm, cen, Upk, Wpk, ec);
    gmm_fused<<<dim3(B_N / 32), dim3(512), 0, stream>>>(x, Upk, Wpk, ec, out);
}